// Round 1
// baseline (1994.632 us; speedup 1.0000x reference)
//
#include <hip/hip_runtime.h>
#include <hip/hip_bf16.h>
#include <stdint.h>

#define TOK  8192
#define DIN  4096
#define DOUT 4096
#define NPL  3

typedef unsigned short u16;
typedef __attribute__((ext_vector_type(8))) __bf16 bf16x8;
typedef __attribute__((ext_vector_type(4))) float f32x4;
typedef __attribute__((ext_vector_type(4))) unsigned short u16x4;

// ADC_MUL = (0.6/127) * 8020 * 256  (fold DAC step + OUT_SCALE + 1/step into one mul)
#define ADC_MUL   9699.7795275590551f
#define INV256    0.00390625f

__device__ __forceinline__ void gload_lds16(const void* g, void* l) {
    __builtin_amdgcn_global_load_lds(
        (const __attribute__((address_space(1))) void*)g,
        (__attribute__((address_space(3))) void*)l, 16, 0, 0);
}

// ---------------- Kernel 1: DAC  x (f32) -> k (bf16 integer levels) ----------------
// inp = 0.6 * round(clip(x*0.15,-1,1)*127)/127 = (0.6/127)*k ; store k exactly in bf16.
__global__ void dac_kernel(const float* __restrict__ x, u16* __restrict__ a) {
    const int n4 = TOK * DIN / 4;
    int i = blockIdx.x * blockDim.x + threadIdx.x;
    const int stride = gridDim.x * blockDim.x;
    const float4* xv = (const float4*)x;
    u16x4* av = (u16x4*)a;
    for (; i < n4; i += stride) {
        float4 v = xv[i];
        u16x4 o;
        float t, k;
        t = v.x * 0.15f; t = fminf(1.0f, fmaxf(-1.0f, t)); k = rintf(t * 127.0f);
        o.x = (u16)(__float_as_uint(k) >> 16);     // exact: |k|<=127 integer, low bits 0
        t = v.y * 0.15f; t = fminf(1.0f, fmaxf(-1.0f, t)); k = rintf(t * 127.0f);
        o.y = (u16)(__float_as_uint(k) >> 16);
        t = v.z * 0.15f; t = fminf(1.0f, fmaxf(-1.0f, t)); k = rintf(t * 127.0f);
        o.z = (u16)(__float_as_uint(k) >> 16);
        t = v.w * 0.15f; t = fminf(1.0f, fmaxf(-1.0f, t)); k = rintf(t * 127.0f);
        o.w = (u16)(__float_as_uint(k) >> 16);
        av[i] = o;
    }
}

// ---------------- Kernel 2: w_eff = w_pos - w_neg -> hi/lo bf16, transposed [p][o][i] ----
__global__ void wsplit_kernel(const float* __restrict__ wp, const float* __restrict__ wn,
                              u16* __restrict__ whi, u16* __restrict__ wlo) {
    __shared__ float tile[64][65];                 // +1 pad: conflict-free transpose
    const int b   = blockIdx.x;
    const int p   = b >> 12;                       // / (64*64)
    const int rem = b & 4095;
    const int ib  = rem >> 6, ob = rem & 63;
    const size_t plane = (size_t)p * DIN * DOUT;
    const int tx = threadIdx.x & 63, ty = threadIdx.x >> 6;

#pragma unroll
    for (int r = ty; r < 64; r += 4) {
        size_t off = plane + (size_t)(ib * 64 + r) * DOUT + ob * 64 + tx;
        tile[r][tx] = wp[off] - wn[off];
    }
    __syncthreads();
#pragma unroll
    for (int r = ty; r < 64; r += 4) {
        float d = tile[tx][r];                     // transposed read (o-major out)
        uint32_t db = __float_as_uint(d);
        uint32_t hb = (db + 0x7fffu + ((db >> 16) & 1u)) & 0xffff0000u;  // RNE to bf16
        float hf = __uint_as_float(hb);
        float l  = d - hf;                         // exact (Sterbenz)
        uint32_t lb = __float_as_uint(l);
        u16 lo16 = (u16)((lb + 0x7fffu + ((lb >> 16) & 1u)) >> 16);
        size_t off = plane + (size_t)(ob * 64 + r) * DIN + ib * 64 + tx;
        whi[off] = (u16)(hb >> 16);
        wlo[off] = lo16;
    }
}

// ---------------- Kernel 3: fused GEMM (3 planes x {hi,lo}) + ADC + shift-acc + bias ----
// 128x128 tile, BK=64, 4 waves (2x2), each wave 64x64 via 4x4 fragments of 16x16x32.
__global__ __launch_bounds__(256, 2) void gemm_kernel(
    const u16* __restrict__ A,      // [8192][4096] bf16 (k values)
    const u16* __restrict__ Whi,    // [3][4096 o][4096 i] bf16
    const u16* __restrict__ Wlo,    // [3][4096 o][4096 i] bf16
    const float* __restrict__ bias, // [4096]
    float* __restrict__ out)        // [8192][4096] f32
{
    __shared__ __align__(16) char lds[49152];      // A 16K | Bhi 16K | Blo 16K
    char* sA = lds;
    char* sH = lds + 16384;
    char* sL = lds + 32768;

    // XCD-aware bijective swizzle: 2048 blocks, 8 XCDs, m-fastest within chunk.
    const int bid  = blockIdx.x;
    const int swz  = ((bid & 7) << 8) | (bid >> 3);
    const int mblk = swz & 63, nblk = swz >> 6;
    const int row0 = mblk << 7, col0 = nblk << 7;

    const int tid  = threadIdx.x;
    const int lane = tid & 63, wid = tid >> 6;
    const int wm = wid & 1, wn = wid >> 1;

    // staging constants: chunk c = it*256 + tid ; row=c>>3 ; colbyte=(c&7)<<4
    // LDS stays linear; SOURCE column pre-swizzled by ^((row&7)<<4)  (guide G4/m173)
    const int rbase = tid >> 3;                                    // 0..31
    const int scb   = (((tid & 7) ^ ((tid >> 3) & 7)) << 4);
    const char* gA = (const char*)A;

    // fragment-read constants (row&7 == lane&7 for all fragments)
    const int arow = (wm << 6) + (lane & 15);
    const int brow = (wn << 6) + (lane & 15);
    const int ksw  = (lane & 7) << 4;
    const int kb   = (lane >> 4) << 4;             // this lane's 16B within a 64B k-slab
    const int koff0 = kb ^ ksw;
    const int koff1 = (64 + kb) ^ ksw;

    f32x4 fin[4][4];
#pragma unroll
    for (int i = 0; i < 4; ++i)
#pragma unroll
        for (int j = 0; j < 4; ++j) fin[i][j] = (f32x4){0.f, 0.f, 0.f, 0.f};

    const float shifts[NPL] = {4.0f, 2.0f, 1.0f};

    for (int p = 0; p < NPL; ++p) {
        const char* baseH = (const char*)Whi + (size_t)p * DIN * DOUT * 2;
        const char* baseL = (const char*)Wlo + (size_t)p * DIN * DOUT * 2;

        f32x4 acc[4][4];
#pragma unroll
        for (int i = 0; i < 4; ++i)
#pragma unroll
            for (int j = 0; j < 4; ++j) acc[i][j] = (f32x4){0.f, 0.f, 0.f, 0.f};

        for (int kt = 0; kt < DIN / 64; ++kt) {
            const int kcb = kt << 7;               // K-tile start, bytes
#pragma unroll
            for (int it = 0; it < 4; ++it) {
                const int r = (it << 5) + rbase;   // tile row 0..127
                const int ldst = (it << 12) + (wid << 10);          // wave-uniform LDS base
                const size_t aoff = (size_t)(row0 + r) * (DIN * 2) + kcb + scb;
                gload_lds16(gA + aoff, sA + ldst);
                const size_t woff = (size_t)(col0 + r) * (DIN * 2) + kcb + scb;
                gload_lds16(baseH + woff, sH + ldst);
                gload_lds16(baseL + woff, sL + ldst);
            }
            __syncthreads();

#pragma unroll
            for (int ks = 0; ks < 2; ++ks) {
                const int ko = ks ? koff1 : koff0;
                bf16x8 av[4], hv[4], lv[4];
#pragma unroll
                for (int mi = 0; mi < 4; ++mi)
                    av[mi] = *(const bf16x8*)(sA + ((arow + (mi << 4)) << 7) + ko);
#pragma unroll
                for (int ni = 0; ni < 4; ++ni) {
                    hv[ni] = *(const bf16x8*)(sH + ((brow + (ni << 4)) << 7) + ko);
                    lv[ni] = *(const bf16x8*)(sL + ((brow + (ni << 4)) << 7) + ko);
                }
#pragma unroll
                for (int mi = 0; mi < 4; ++mi)
#pragma unroll
                    for (int ni = 0; ni < 4; ++ni) {
                        acc[mi][ni] = __builtin_amdgcn_mfma_f32_16x16x32_bf16(
                            av[mi], hv[ni], acc[mi][ni], 0, 0, 0);
                        acc[mi][ni] = __builtin_amdgcn_mfma_f32_16x16x32_bf16(
                            av[mi], lv[ni], acc[mi][ni], 0, 0, 0);
                    }
            }
            __syncthreads();
        }

        // ADC per plane, then shift-accumulate (exact in f32: 15-bit grid values)
        const float sh = shifts[p];
#pragma unroll
        for (int mi = 0; mi < 4; ++mi)
#pragma unroll
            for (int ni = 0; ni < 4; ++ni)
#pragma unroll
                for (int r = 0; r < 4; ++r) {
                    float q = rintf(acc[mi][ni][r] * ADC_MUL) * INV256;
                    q = fminf(16.0f, fmaxf(-16.0f, q));
                    fin[mi][ni][r] += sh * q;
                }
    }

    // epilogue: out = mem_out * 0.01 + bias   (C/D layout: col=lane&15, row=(lane>>4)*4+r)
    const int orow = row0 + (wm << 6) + ((lane >> 4) << 2);
    const int ocol = col0 + (wn << 6) + (lane & 15);
#pragma unroll
    for (int ni = 0; ni < 4; ++ni) {
        const int c = ocol + (ni << 4);
        const float bv = bias[c];
#pragma unroll
        for (int mi = 0; mi < 4; ++mi)
#pragma unroll
            for (int r = 0; r < 4; ++r)
                out[(size_t)(orow + (mi << 4) + r) * DOUT + c] = fin[mi][ni][r] * 0.01f + bv;
    }
}

extern "C" void kernel_launch(void* const* d_in, const int* in_sizes, int n_in,
                              void* d_out, int out_size, void* d_ws, size_t ws_size,
                              hipStream_t stream) {
    const float* x    = (const float*)d_in[0];
    const float* wp   = (const float*)d_in[1];
    const float* wn   = (const float*)d_in[2];
    const float* bias = (const float*)d_in[3];
    float* out = (float*)d_out;

    u16* A   = (u16*)d_ws;                                // 8192*4096 bf16 = 67 MB
    u16* Whi = A + (size_t)TOK * DIN;                     // 3*4096*4096 bf16 = 100.7 MB
    u16* Wlo = Whi + (size_t)NPL * DIN * DOUT;            // 100.7 MB   (total 268.4 MB)

    dac_kernel<<<dim3(4096), dim3(256), 0, stream>>>(x, A);
    wsplit_kernel<<<dim3(NPL * 64 * 64), dim3(256), 0, stream>>>(wp, wn, Whi, Wlo);
    gemm_kernel<<<dim3(2048), dim3(256), 0, stream>>>(A, Whi, Wlo, bias, out);
}